// Round 9
// baseline (4095.297 us; speedup 1.0000x reference)
//
#include <hip/hip_runtime.h>
#include <hip/hip_bf16.h>
#include <float.h>
#include <math.h>

#define BSZ    32
#define SRCLEN 128
#define DM     512
#define VOCAB  50257
#define VB     393            // vocab blocks of 128 (393*128 = 50304)
#define TGT    48             // max_tgt_len
#define TOKC   50             // TGT+2
#define SCC    49             // TGT+1
#define PAD_ID 1
#define UNK_ID 3
#define EOS_ID 2
#define NEG    (-1e30f)

typedef __attribute__((ext_vector_type(8))) short bf16x8;
typedef __attribute__((ext_vector_type(4))) float f32x4;

// ---------------------------------------------------------------- helpers
__device__ inline unsigned pkbf(float lo, float hi) {
    unsigned a = __float_as_uint(lo), b = __float_as_uint(hi);
    a = (a + 0x7fffu + ((a >> 16) & 1u)) >> 16;
    b = (b + 0x7fffu + ((b >> 16) & 1u)) >> 16;
    return (a & 0xffffu) | (b << 16);
}

__device__ inline unsigned short f2bf(float x) {
    unsigned u = __float_as_uint(x);
    u = (u + 0x7fffu + ((u >> 16) & 1u)) >> 16;
    return (unsigned short)u;
}

__device__ inline void ce_pair(float& av, int& ai, float& bv, int& bi) {
    bool keep = (av > bv) || (av == bv && ai < bi);
    if (!keep) {
        float tv = av; av = bv; bv = tv;
        int ti = ai; ai = bi; bi = ti;
    }
}

// FULL 8-stage bitonic merge (R1 verbatim).
__device__ inline void merge4(float a0v[4], int a0i[4], float bv[4], int bi[4]) {
    float e[8]; int ix[8];
#pragma unroll
    for (int c = 0; c < 4; c++) { e[c] = a0v[c]; ix[c] = a0i[c]; e[4 + c] = bv[c]; ix[4 + c] = bi[c]; }
    ce_pair(e[0], ix[0], e[4], ix[4]); ce_pair(e[1], ix[1], e[5], ix[5]);
    ce_pair(e[2], ix[2], e[6], ix[6]); ce_pair(e[3], ix[3], e[7], ix[7]);
    ce_pair(e[2], ix[2], e[4], ix[4]); ce_pair(e[3], ix[3], e[5], ix[5]);
    ce_pair(e[1], ix[1], e[2], ix[2]); ce_pair(e[3], ix[3], e[4], ix[4]);
#pragma unroll
    for (int c = 0; c < 4; c++) { a0v[c] = e[c]; a0i[c] = ix[c]; }
}

__device__ inline void osm_merge(float& m, float& s, float om, float os) {
    float nm = fmaxf(m, om);
    float sa = (m == -FLT_MAX) ? 0.f : s * expf(m - nm);
    float sb = (om == -FLT_MAX) ? 0.f : os * expf(om - nm);
    s = sa + sb; m = nm;
}

// ----------------------------------------------------- embed fp32 -> bf16
__global__ void embed2bf_kernel(const float* __restrict__ e,
                                unsigned short* __restrict__ o) {
    size_t i = ((size_t)blockIdx.x * 256 + threadIdx.x) * 8;
    if (i >= (size_t)VOCAB * DM) return;
    float4 a = *(const float4*)(e + i);
    float4 b = *(const float4*)(e + i + 4);
    uint4 r = { pkbf(a.x, a.y), pkbf(a.z, a.w), pkbf(b.x, b.y), pkbf(b.z, b.w) };
    *(uint4*)(o + i) = r;
}

// ---------------------------------------------------------------- ctx partial
// R9: R7's 512-thread kernel with the wenc loads software-pipelined depth-2
// (load the k+4 group before consuming the k group), same trick as the gemm.
// FMA statements and their order are IDENTICAL to R7 (bit-identical result);
// only load issue points move earlier so L2 latency hides under FMA work.
// Zero workspace change (R8's k-split scratch is abandoned — suspected
// workspace overflow killed the container).
__global__ void __launch_bounds__(512)
ctx_partial_kernel(const int* __restrict__ src,
                   const float* __restrict__ embed,
                   const float* __restrict__ wenc,
                   float* __restrict__ partial) {
    int b = blockIdx.x, jc = blockIdx.y, t = threadIdx.x;   // t < 512
    __shared__ float e[16][DM];                             // 32 KB
    for (int jj = 0; jj < 16; jj++) {
        int tok = src[b * SRCLEN + jc * 16 + jj];
        e[jj][t] = embed[(size_t)tok * DM + t];
    }
    __syncthreads();
    float a0[16];
#pragma unroll
    for (int jj = 0; jj < 16; jj++) a0[jj] = 0.f;

    float wa[4], wb[4];
#pragma unroll
    for (int q = 0; q < 4; q++) wa[q] = wenc[q * DM + t];
    for (int k = 0; k < DM; k += 8) {
        // prefetch k+4 group (consumed below, after the k-group FMAs)
#pragma unroll
        for (int q = 0; q < 4; q++) wb[q] = wenc[(k + 4 + q) * DM + t];
#pragma unroll
        for (int jj = 0; jj < 16; jj++) {
            float4 ev = *(const float4*)&e[jj][k];
            a0[jj] += ev.x * wa[0]; a0[jj] += ev.y * wa[1];
            a0[jj] += ev.z * wa[2]; a0[jj] += ev.w * wa[3];
        }
        // prefetch k+8 group (consumed next iteration)
        if (k + 8 < DM) {
#pragma unroll
            for (int q = 0; q < 4; q++) wa[q] = wenc[(k + 8 + q) * DM + t];
        }
#pragma unroll
        for (int jj = 0; jj < 16; jj++) {
            float4 ev = *(const float4*)&e[jj][k + 4];
            a0[jj] += ev.x * wb[0]; a0[jj] += ev.y * wb[1];
            a0[jj] += ev.z * wb[2]; a0[jj] += ev.w * wb[3];
        }
    }
    float s0 = 0.f;
#pragma unroll
    for (int jj = 0; jj < 16; jj++) s0 += tanhf(a0[jj]);
    partial[(size_t)(b * 8 + jc) * DM + t] = s0;
}

__global__ void ctx_reduce_kernel(const float* __restrict__ partial,
                                  float* __restrict__ ctx) {
    int b = blockIdx.x, t = threadIdx.x;
    float s = 0.f;
    for (int jc = 0; jc < 8; jc++) s += partial[(size_t)(b * 8 + jc) * DM + t];
    ctx[b * DM + t] = s * (1.0f / 128.0f);
}

// ---------------------------------------------------------------- hidden h0
// Prologue only (step 0, all rows EOS); R1 verbatim.
__global__ void hidden_kernel(const float* __restrict__ embed,
                              const float* __restrict__ wdec,
                              const float* __restrict__ bdec,
                              const float* __restrict__ ctx,
                              unsigned short* __restrict__ h) {
    int t = threadIdx.x;                 // 0..127
    int r0 = blockIdx.x * 4;
    int d = blockIdx.y * 128 + t;
    __shared__ float e[4][DM];
    for (int i = 0; i < 4; i++) {
        for (int c = t; c < DM; c += 128)
            e[i][c] = embed[(size_t)EOS_ID * DM + c];
    }
    __syncthreads();
    float acc[4] = {0.f, 0.f, 0.f, 0.f};
#pragma unroll 2
    for (int k = 0; k < DM; k += 4) {
        float w[4];
#pragma unroll
        for (int q = 0; q < 4; q++) w[q] = wdec[(k + q) * DM + d];
#pragma unroll
        for (int i = 0; i < 4; i++) {
            float4 ev = *(const float4*)&e[i][k];
            acc[i] += ev.x * w[0]; acc[i] += ev.y * w[1];
            acc[i] += ev.z * w[2]; acc[i] += ev.w * w[3];
        }
    }
    float bb = bdec[d];
#pragma unroll
    for (int i = 0; i < 4; i++) {
        int r = r0 + i;
        int sent = (r & 31);
        h[r * DM + d] = f2bf(tanhf(acc[i] + bb + ctx[sent * DM + d]));
    }
}

// ----------------------------------- MFMA logits GEMM + fused softmax/top4
// R1 verbatim (measured-best staging).
__global__ void __launch_bounds__(256, 2)
gemm_topk(const unsigned short* __restrict__ hb,
          const unsigned short* __restrict__ ebf,
          float* __restrict__ pm, float* __restrict__ ps,
          float* __restrict__ pv, int* __restrict__ pi,
          int step0, int ensure) {
    __shared__ char smem[16384];
    short* As = (short*)smem;
    short* Bs = (short*)(smem + 8192);
    int t = threadIdx.x;
    int v0 = blockIdx.x * 128;
    int w = t >> 6, lane = t & 63;
    int quad = lane >> 4, lr = lane & 15;
    int vh = w & 1, hh = w >> 1;
    int row2 = t >> 1, khalf = t & 1;

    f32x4 acc[4][4];
#pragma unroll
    for (int i = 0; i < 4; i++)
#pragma unroll
        for (int j = 0; j < 4; j++) acc[i][j] = (f32x4){0.f, 0.f, 0.f, 0.f};

    int arow = v0 + row2;
    bool aval = arow < VOCAB;
    const unsigned short* ga = ebf + (size_t)(aval ? arow : 0) * DM + khalf * 16;
    const unsigned short* gb = hb + row2 * DM + khalf * 16;

    uint4 a0_0 = *(const uint4*)(ga);
    uint4 a1_0 = *(const uint4*)(ga + 8);
    uint4 b0_0 = *(const uint4*)(gb);
    uint4 b1_0 = *(const uint4*)(gb + 8);
    uint4 a0_1 = *(const uint4*)(ga + 32);
    uint4 a1_1 = *(const uint4*)(ga + 40);
    uint4 b0_1 = *(const uint4*)(gb + 32);
    uint4 b1_1 = *(const uint4*)(gb + 40);

    auto kstep = [&](uint4& A0, uint4& A1, uint4& B0, uint4& B1, int kc) {
        if (!aval) {
            A0 = make_uint4(0u, 0u, 0u, 0u);
            A1 = make_uint4(0u, 0u, 0u, 0u);
        }
        __syncthreads();
        *(uint4*)(As + (khalf * 2) * 1024 + row2 * 8)     = A0;
        *(uint4*)(As + (khalf * 2 + 1) * 1024 + row2 * 8) = A1;
        *(uint4*)(Bs + (khalf * 2) * 1024 + row2 * 8)     = B0;
        *(uint4*)(Bs + (khalf * 2 + 1) * 1024 + row2 * 8) = B1;
        __syncthreads();
        if (kc + 64 < DM) {
            A0 = *(const uint4*)(ga + kc + 64);
            A1 = *(const uint4*)(ga + kc + 72);
            B0 = *(const uint4*)(gb + kc + 64);
            B1 = *(const uint4*)(gb + kc + 72);
        }
        bf16x8 af[4], bfr[4];
#pragma unroll
        for (int i = 0; i < 4; i++)
            af[i] = *(bf16x8*)(As + quad * 1024 + (64 * vh + 16 * i + lr) * 8);
#pragma unroll
        for (int j = 0; j < 4; j++)
            bfr[j] = *(bf16x8*)(Bs + quad * 1024 + (64 * hh + 16 * j + lr) * 8);
#pragma unroll
        for (int i = 0; i < 4; i++)
#pragma unroll
            for (int j = 0; j < 4; j++)
                acc[i][j] = __builtin_amdgcn_mfma_f32_16x16x32_bf16(
                    af[i], bfr[j], acc[i][j], 0, 0, 0);
    };

#pragma unroll
    for (int kc = 0; kc < DM; kc += 64) {
        kstep(a0_0, a1_0, b0_0, b1_0, kc);
        kstep(a0_1, a1_1, b0_1, b1_1, kc + 32);
    }
    __syncthreads();

    float* epim = (float*)smem;            // [128][2]
    float* epis = (float*)(smem + 1024);   // [128][2]
    float* epiv = (float*)(smem + 2048);   // [128][2][4]
    int*   epii = (int*)(smem + 6144);     // [128][2][4]

#pragma unroll
    for (int j = 0; j < 4; j++) {
        float m = -FLT_MAX, ssum = 0.f;
        float tv4[4] = {-FLT_MAX, -FLT_MAX, -FLT_MAX, -FLT_MAX};
        int ti4[4] = {0x7fffffff, 0x7fffffff, 0x7fffffff, 0x7fffffff};
#pragma unroll
        for (int i = 0; i < 4; i++)
#pragma unroll
            for (int reg = 0; reg < 4; reg++) {
                int v = v0 + 64 * vh + 16 * i + quad * 4 + reg;
                if (v < VOCAB) m = fmaxf(m, acc[i][j][reg]);
            }
#pragma unroll
        for (int i = 0; i < 4; i++)
#pragma unroll
            for (int reg = 0; reg < 4; reg++) {
                int v = v0 + 64 * vh + 16 * i + quad * 4 + reg;  // ascending
                if (v >= VOCAB) continue;
                float raw = acc[i][j][reg];
                ssum += __expf(raw - m);
                float mv = raw;
                if (v == PAD_ID) mv = NEG;
                if (step0 && v == EOS_ID) mv = NEG;
                if (ensure && v != EOS_ID) mv = NEG;
                if (mv > tv4[3]) {   // strict > keeps earliest (smallest v)
                    tv4[3] = mv; ti4[3] = v;
                    if (tv4[3] > tv4[2]) { float a = tv4[3]; tv4[3] = tv4[2]; tv4[2] = a; int b = ti4[3]; ti4[3] = ti4[2]; ti4[2] = b; }
                    if (tv4[2] > tv4[1]) { float a = tv4[2]; tv4[2] = tv4[1]; tv4[1] = a; int b = ti4[2]; ti4[2] = ti4[1]; ti4[1] = b; }
                    if (tv4[1] > tv4[0]) { float a = tv4[1]; tv4[1] = tv4[0]; tv4[0] = a; int b = ti4[1]; ti4[1] = ti4[0]; ti4[0] = b; }
                }
            }
#pragma unroll
        for (int mask = 16; mask <= 32; mask <<= 1) {
            float om = __shfl_xor(m, mask);
            float os = __shfl_xor(ssum, mask);
            float ov[4]; int oi[4];
#pragma unroll
            for (int c = 0; c < 4; c++) {
                ov[c] = __shfl_xor(tv4[c], mask);
                oi[c] = __shfl_xor(ti4[c], mask);
            }
            osm_merge(m, ssum, om, os);
            merge4(tv4, ti4, ov, oi);
        }
        if (quad == 0) {
            int hrow = 64 * hh + 16 * j + lr;
            int slot = hrow * 2 + vh;
            epim[slot] = m; epis[slot] = ssum;
#pragma unroll
            for (int c = 0; c < 4; c++) { epiv[slot * 4 + c] = tv4[c]; epii[slot * 4 + c] = ti4[c]; }
        }
    }
    __syncthreads();
    if (t < 128) {
        int s0 = t * 2, s1 = t * 2 + 1;
        float m = epim[s0], ssum = epis[s0];
        float tv4[4]; int ti4[4];
#pragma unroll
        for (int c = 0; c < 4; c++) { tv4[c] = epiv[s0 * 4 + c]; ti4[c] = epii[s0 * 4 + c]; }
        float ov[4]; int oi[4];
#pragma unroll
        for (int c = 0; c < 4; c++) { ov[c] = epiv[s1 * 4 + c]; oi[c] = epii[s1 * 4 + c]; }
        osm_merge(m, ssum, epim[s1], epis[s1]);
        merge4(tv4, ti4, ov, oi);
        int pidx = t * VB + blockIdx.x;
        pm[pidx] = m;
        ps[pidx] = ssum;
#pragma unroll
        for (int c = 0; c < 4; c++) { pv[pidx * 4 + c] = tv4[c]; pi[pidx * 4 + c] = ti4[c]; }
    }
}

// ------------------------------------------- fused beam update + next hidden
// R7 verbatim (128 blocks; redundant deterministic beam update per sentence,
// ping-pong pscore/bestfin to avoid redundancy races).
__global__ void __launch_bounds__(256)
beamhid(int s,
        const float* __restrict__ pm, const float* __restrict__ ps,
        const float* __restrict__ pv, const int* __restrict__ pi,
        const int* __restrict__ tok_cur, int* __restrict__ tok_nxt,
        const float* __restrict__ sc_cur, float* __restrict__ sc_nxt,
        const float* __restrict__ psc_cur, float* __restrict__ psc_nxt,
        const float* __restrict__ bf_cur, float* __restrict__ bf_nxt,
        const float* __restrict__ embed,
        const float* __restrict__ wdec,
        const float* __restrict__ bdec,
        const float* __restrict__ ctxv,
        unsigned short* __restrict__ h) {
    int blk = blockIdx.x, t = threadIdx.x;
    int rg = blk >> 2, q = blk & 3;
    __shared__ float r_cs[16], r_sent[16], r_ssel[4];
    __shared__ int r_ct[16], r_parent[4], r_tsel[4];
    __shared__ float e[4][DM];

    if (s == 0) {
        if (t < 64) {
            int lane = t;
            float m = -FLT_MAX, ssum = 0.f;
            float tv4[4] = {-FLT_MAX, -FLT_MAX, -FLT_MAX, -FLT_MAX};
            int ti4[4] = {0x7fffffff, 0x7fffffff, 0x7fffffff, 0x7fffffff};
            for (int j = lane; j < VB; j += 64) {
                int pidx = rg * VB + j;
                float ov[4]; int oi[4];
#pragma unroll
                for (int c = 0; c < 4; c++) { ov[c] = pv[pidx * 4 + c]; oi[c] = pi[pidx * 4 + c]; }
                osm_merge(m, ssum, pm[pidx], ps[pidx]);
                merge4(tv4, ti4, ov, oi);
            }
#pragma unroll
            for (int mask = 1; mask <= 32; mask <<= 1) {
                float om = __shfl_xor(m, mask);
                float os = __shfl_xor(ssum, mask);
                float ov[4]; int oi[4];
#pragma unroll
                for (int c = 0; c < 4; c++) {
                    ov[c] = __shfl_xor(tv4[c], mask);
                    oi[c] = __shfl_xor(ti4[c], mask);
                }
                osm_merge(m, ssum, om, os);
                merge4(tv4, ti4, ov, oi);
            }
            if (lane == 0) {
                float lse_b = m + logf(ssum);
                for (int c = 0; c < 4; c++) {
                    float val = tv4[c];
                    float sc = (val < -9.0e29f) ? NEG : (val - lse_b);
                    if (sc < -9.0e29f) sc = NEG;
                    r_tsel[c] = ti4[c]; r_ssel[c] = sc;
                    psc_nxt[rg * 4 + c] = sc;
                }
                bf_nxt[rg] = NEG;
            }
        }
        __syncthreads();
        for (int idx = t; idx < 4 * TOKC; idx += 256) {
            int i = idx / TOKC, c = idx % TOKC;
            int dst = rg * 4 + i;
            tok_nxt[dst * TOKC + c] = (c == 0) ? EOS_ID : ((c == 1) ? r_tsel[i] : PAD_ID);
            if (c < SCC) sc_nxt[dst * SCC + c] = (c == 0) ? r_ssel[i] : NEG;
        }
    } else {
        int g = t >> 6, lane = t & 63;
        int r = rg * 4 + g;
        float m = -FLT_MAX, ssum = 0.f;
        float tv4[4] = {-FLT_MAX, -FLT_MAX, -FLT_MAX, -FLT_MAX};
        int ti4[4] = {0x7fffffff, 0x7fffffff, 0x7fffffff, 0x7fffffff};
        for (int j = lane; j < VB; j += 64) {
            int pidx = r * VB + j;
            float ov[4]; int oi[4];
#pragma unroll
            for (int c = 0; c < 4; c++) { ov[c] = pv[pidx * 4 + c]; oi[c] = pi[pidx * 4 + c]; }
            osm_merge(m, ssum, pm[pidx], ps[pidx]);
            merge4(tv4, ti4, ov, oi);
        }
#pragma unroll
        for (int mask = 1; mask <= 32; mask <<= 1) {
            float om = __shfl_xor(m, mask);
            float os = __shfl_xor(ssum, mask);
            float ov[4]; int oi[4];
#pragma unroll
            for (int c = 0; c < 4; c++) {
                ov[c] = __shfl_xor(tv4[c], mask);
                oi[c] = __shfl_xor(ti4[c], mask);
            }
            osm_merge(m, ssum, om, os);
            merge4(tv4, ti4, ov, oi);
        }
        if (lane == 0) {
            float lse_r = m + logf(ssum);
            float prev = psc_cur[r];
            for (int c = 0; c < 4; c++) {
                float val = tv4[c];
                float lp = (val < -9.0e29f) ? NEG : (val - lse_r);
                float csv = lp + prev;
                if (csv < -9.0e29f) csv = NEG;
                r_cs[g * 4 + c] = csv;
                r_sent[g * 4 + c] = csv / (float)(s + 1);
                r_ct[g * 4 + c] = ti4[c];
            }
        }
        __syncthreads();
        if (t == 0) {
            int top[8], c2[8];
            float s2[8], cs2[8];
            unsigned used = 0;
            for (int o = 0; o < 8; o++) {
                float best = -FLT_MAX; int bi = 0;
                for (int i = 0; i < 16; i++)
                    if (!((used >> i) & 1u) && r_sent[i] > best) { best = r_sent[i]; bi = i; }
                used |= 1u << bi;
                top[o] = bi; s2[o] = best; c2[o] = r_ct[bi]; cs2[o] = r_cs[bi];
            }
            float bf = bf_cur[rg];
            for (int c = 0; c < 4; c++)
                if (c2[c] == EOS_ID) bf = fmaxf(bf, s2[c]);
            bf_nxt[rg] = bf;
            float sm[8];
            for (int c = 0; c < 8; c++) sm[c] = (c2[c] == EOS_ID) ? NEG : s2[c];
            unsigned used2 = 0;
            for (int o = 0; o < 4; o++) {
                float best = -FLT_MAX; int bi = 0;
                for (int i = 0; i < 8; i++)
                    if (!((used2 >> i) & 1u) && sm[i] > best) { best = sm[i]; bi = i; }
                used2 |= 1u << bi;
                r_parent[o] = top[bi] >> 2;
                r_tsel[o] = c2[bi];
                float sv = cs2[bi];
                if (sv < -9.0e29f) sv = NEG;
                r_ssel[o] = sv;
            }
            for (int o = 0; o < 4; o++)
                psc_nxt[rg * 4 + o] = r_ssel[o];
        }
        __syncthreads();
        for (int idx = t; idx < 4 * TOKC; idx += 256) {
            int i = idx / TOKC, c = idx % TOKC;
            int srcr = rg * 4 + r_parent[i], dst = rg * 4 + i;
            tok_nxt[dst * TOKC + c] = (c == s + 1) ? r_tsel[i] : tok_cur[srcr * TOKC + c];
            if (c < SCC)
                sc_nxt[dst * SCC + c] = (c == s) ? r_ssel[i] : sc_cur[srcr * SCC + c];
        }
    }

    // ---- next-step h rows for sentence rg, col slice q ----
    if (s < TGT) {
        __syncthreads();
        for (int i = 0; i < 4; i++) {
            int tok = r_tsel[i];
            for (int c = t; c < DM; c += 256)
                e[i][c] = embed[(size_t)tok * DM + c];
        }
        __syncthreads();
        if (t < 128) {
            int d = q * 128 + t;
            float acc[4] = {0.f, 0.f, 0.f, 0.f};
#pragma unroll 2
            for (int k = 0; k < DM; k += 4) {
                float w[4];
#pragma unroll
                for (int qq = 0; qq < 4; qq++) w[qq] = wdec[(k + qq) * DM + d];
#pragma unroll
                for (int i = 0; i < 4; i++) {
                    float4 ev = *(const float4*)&e[i][k];
                    acc[i] += ev.x * w[0]; acc[i] += ev.y * w[1];
                    acc[i] += ev.z * w[2]; acc[i] += ev.w * w[3];
                }
            }
            float bb = bdec[d];
#pragma unroll
            for (int i = 0; i < 4; i++) {
                int r = rg * 4 + i;
                h[r * DM + d] = f2bf(tanhf(acc[i] + bb + ctxv[rg * DM + d]));
            }
        }
    }
}

// ---------------------------------------------------------------- finalize
__global__ void finalize_kernel(const int* __restrict__ tok,
                                const float* __restrict__ sc,
                                const float* __restrict__ bf,
                                float* __restrict__ out) {
    int i = blockIdx.x * 256 + threadIdx.x;
    const int NTOK = 128 * TOKC;        // 6400
    const int NSC = 128 * SCC;          // 6272
    const int TOT = NTOK + NSC + 32;    // 12704
    if (i >= TOT) return;
    float v;
    if (i < NTOK) {
        int tv = tok[i];
        if (tv < 0) tv = 0;
        if (tv > VOCAB - 1) tv = VOCAB - 1;
        v = (float)tv;
    } else {
        v = (i < NTOK + NSC) ? sc[i - NTOK] : bf[i - NTOK - NSC];
        if (!(v <= 0.0f)) v = 0.0f;
        if (v < -9.0e29f) v = NEG;
    }
    out[i] = v;
}

// ---------------------------------------------------------------- launch
extern "C" void kernel_launch(void* const* d_in, const int* in_sizes, int n_in,
                              void* d_out, int out_size, void* d_ws, size_t ws_size,
                              hipStream_t stream) {
    const int* src = (const int*)d_in[0];
    const float* embed = (const float*)d_in[1];
    const float* wenc = (const float*)d_in[2];
    const float* wdec = (const float*)d_in[3];
    const float* bdec = (const float*)d_in[4];

    char* w = (char*)d_ws;
    size_t off = 0;
    auto alloc = [&](size_t bytes) -> char* {
        char* p = w + off;
        off += (bytes + 255) & ~(size_t)255;
        return p;
    };
    float* psb0   = (float*)alloc(128 * 4);
    float* psb1   = (float*)alloc(128 * 4);
    float* bfb0   = (float*)alloc(BSZ * 4);
    float* bfb1   = (float*)alloc(BSZ * 4);
    int*   tokb0  = (int*)alloc(128 * TOKC * 4);
    int*   tokb1  = (int*)alloc(128 * TOKC * 4);
    float* scb0   = (float*)alloc(128 * SCC * 4);
    float* scb1   = (float*)alloc(128 * SCC * 4);
    unsigned short* h = (unsigned short*)alloc((size_t)128 * DM * 2);
    float* ctx    = (float*)alloc((size_t)BSZ * DM * 4);
    float* encpart= (float*)alloc((size_t)BSZ * 8 * DM * 4);
    const size_t NP = (size_t)128 * VB;
    float* pm = (float*)alloc(NP * 4);
    float* ps = (float*)alloc(NP * 4);
    float* pv = (float*)alloc(NP * 4 * 4);
    int*   pi = (int*)alloc(NP * 4 * 4);
    unsigned short* ebf = (unsigned short*)alloc((size_t)VOCAB * DM * 2);
    int* tokb[2] = {tokb0, tokb1};
    float* scb[2] = {scb0, scb1};
    float* psb[2] = {psb0, psb1};
    float* bfb[2] = {bfb0, bfb1};

    // one-time embed -> bf16 (RNE identical to old in-gemm pkbf)
    embed2bf_kernel<<<(VOCAB * DM / 8 + 255) / 256, 256, 0, stream>>>(embed, ebf);

    // encoder context (512-thread pipelined variant)
    ctx_partial_kernel<<<dim3(BSZ, 8), 512, 0, stream>>>(src, embed, wenc, encpart);
    ctx_reduce_kernel<<<BSZ, 512, 0, stream>>>(encpart, ctx);

    // step-0 hidden (all rows EOS)
    hidden_kernel<<<dim3(32, 4), 128, 0, stream>>>(embed, wdec, bdec, ctx, h);

    // steps 0..48: gemm+topk, then fused beam-update + next hidden
    for (int s = 0; s <= TGT; s++) {
        gemm_topk<<<VB, 256, 0, stream>>>(h, ebf, pm, ps, pv, pi,
                                          (s == 0) ? 1 : 0, (s == TGT) ? 1 : 0);
        int cur = (s == 0) ? 1 : ((s - 1) & 1);   // s=0: cur unread
        int nxt = s & 1;                           // s=0 -> 0
        beamhid<<<128, 256, 0, stream>>>(s, pm, ps, pv, pi,
                                         tokb[cur], tokb[nxt], scb[cur], scb[nxt],
                                         psb[cur], psb[nxt], bfb[cur], bfb[nxt],
                                         embed, wdec, bdec, ctx, h);
    }

    // final parity: step 48 wrote buffer 0
    finalize_kernel<<<50, 256, 0, stream>>>(tokb[0], scb[0], bfb[0],
                                            (float*)d_out);
}

// Round 10
// 3149.603 us; speedup vs baseline: 1.3003x; 1.3003x over previous
//
#include <hip/hip_runtime.h>
#include <hip/hip_bf16.h>
#include <float.h>
#include <math.h>

#define BSZ    32
#define SRCLEN 128
#define DM     512
#define VOCAB  50257
#define VB     393            // vocab blocks of 128 (393*128 = 50304)
#define TGT    48             // max_tgt_len
#define TOKC   50             // TGT+2
#define SCC    49             // TGT+1
#define PAD_ID 1
#define UNK_ID 3
#define EOS_ID 2
#define NEG    (-1e30f)

typedef __attribute__((ext_vector_type(8))) short bf16x8;
typedef __attribute__((ext_vector_type(4))) float f32x4;

// ---------------------------------------------------------------- helpers
__device__ inline unsigned pkbf(float lo, float hi) {
    unsigned a = __float_as_uint(lo), b = __float_as_uint(hi);
    a = (a + 0x7fffu + ((a >> 16) & 1u)) >> 16;
    b = (b + 0x7fffu + ((b >> 16) & 1u)) >> 16;
    return (a & 0xffffu) | (b << 16);
}

__device__ inline unsigned short f2bf(float x) {
    unsigned u = __float_as_uint(x);
    u = (u + 0x7fffu + ((u >> 16) & 1u)) >> 16;
    return (unsigned short)u;
}

__device__ inline void ce_pair(float& av, int& ai, float& bv, int& bi) {
    bool keep = (av > bv) || (av == bv && ai < bi);
    if (!keep) {
        float tv = av; av = bv; bv = tv;
        int ti = ai; ai = bi; bi = ti;
    }
}

// FULL 8-stage bitonic merge (R1 verbatim).
__device__ inline void merge4(float a0v[4], int a0i[4], float bv[4], int bi[4]) {
    float e[8]; int ix[8];
#pragma unroll
    for (int c = 0; c < 4; c++) { e[c] = a0v[c]; ix[c] = a0i[c]; e[4 + c] = bv[c]; ix[4 + c] = bi[c]; }
    ce_pair(e[0], ix[0], e[4], ix[4]); ce_pair(e[1], ix[1], e[5], ix[5]);
    ce_pair(e[2], ix[2], e[6], ix[6]); ce_pair(e[3], ix[3], e[7], ix[7]);
    ce_pair(e[2], ix[2], e[4], ix[4]); ce_pair(e[3], ix[3], e[5], ix[5]);
    ce_pair(e[1], ix[1], e[2], ix[2]); ce_pair(e[3], ix[3], e[4], ix[4]);
#pragma unroll
    for (int c = 0; c < 4; c++) { a0v[c] = e[c]; a0i[c] = ix[c]; }
}

__device__ inline void osm_merge(float& m, float& s, float om, float os) {
    float nm = fmaxf(m, om);
    float sa = (m == -FLT_MAX) ? 0.f : s * expf(m - nm);
    float sb = (om == -FLT_MAX) ? 0.f : os * expf(om - nm);
    s = sa + sb; m = nm;
}

// async global->LDS, 16B per lane; dest = wave-uniform base + lane*16
// (mechanism verified in R6 — that kernel ran correctly).
__device__ inline void gll16(const void* g, void* l) {
    __builtin_amdgcn_global_load_lds(
        (const __attribute__((address_space(1))) void*)g,
        (__attribute__((address_space(3))) void*)l, 16, 0, 0);
}

// ----------------------------------------------------- embed fp32 -> bf16
__global__ void embed2bf_kernel(const float* __restrict__ e,
                                unsigned short* __restrict__ o) {
    size_t i = ((size_t)blockIdx.x * 256 + threadIdx.x) * 8;
    if (i >= (size_t)VOCAB * DM) return;
    float4 a = *(const float4*)(e + i);
    float4 b = *(const float4*)(e + i + 4);
    uint4 r = { pkbf(a.x, a.y), pkbf(a.z, a.w), pkbf(b.x, b.y), pkbf(b.z, b.w) };
    *(uint4*)(o + i) = r;
}

// ---------------------------------------------------------------- ctx partial
// R9 pipelined variant (dropped below 80us; keep).
__global__ void __launch_bounds__(512)
ctx_partial_kernel(const int* __restrict__ src,
                   const float* __restrict__ embed,
                   const float* __restrict__ wenc,
                   float* __restrict__ partial) {
    int b = blockIdx.x, jc = blockIdx.y, t = threadIdx.x;   // t < 512
    __shared__ float e[16][DM];                             // 32 KB
    for (int jj = 0; jj < 16; jj++) {
        int tok = src[b * SRCLEN + jc * 16 + jj];
        e[jj][t] = embed[(size_t)tok * DM + t];
    }
    __syncthreads();
    float a0[16];
#pragma unroll
    for (int jj = 0; jj < 16; jj++) a0[jj] = 0.f;

    float wa[4], wb[4];
#pragma unroll
    for (int q = 0; q < 4; q++) wa[q] = wenc[q * DM + t];
    for (int k = 0; k < DM; k += 8) {
#pragma unroll
        for (int q = 0; q < 4; q++) wb[q] = wenc[(k + 4 + q) * DM + t];
#pragma unroll
        for (int jj = 0; jj < 16; jj++) {
            float4 ev = *(const float4*)&e[jj][k];
            a0[jj] += ev.x * wa[0]; a0[jj] += ev.y * wa[1];
            a0[jj] += ev.z * wa[2]; a0[jj] += ev.w * wa[3];
        }
        if (k + 8 < DM) {
#pragma unroll
            for (int q = 0; q < 4; q++) wa[q] = wenc[(k + 8 + q) * DM + t];
        }
#pragma unroll
        for (int jj = 0; jj < 16; jj++) {
            float4 ev = *(const float4*)&e[jj][k + 4];
            a0[jj] += ev.x * wb[0]; a0[jj] += ev.y * wb[1];
            a0[jj] += ev.z * wb[2]; a0[jj] += ev.w * wb[3];
        }
    }
    float s0 = 0.f;
#pragma unroll
    for (int jj = 0; jj < 16; jj++) s0 += tanhf(a0[jj]);
    partial[(size_t)(b * 8 + jc) * DM + t] = s0;
}

__global__ void ctx_reduce_kernel(const float* __restrict__ partial,
                                  float* __restrict__ ctx) {
    int b = blockIdx.x, t = threadIdx.x;
    float s = 0.f;
    for (int jc = 0; jc < 8; jc++) s += partial[(size_t)(b * 8 + jc) * DM + t];
    ctx[b * DM + t] = s * (1.0f / 128.0f);
}

// ---------------------------------------------------------------- hidden h0
// Prologue only (step 0, all rows EOS); R1 verbatim (runs once).
__global__ void hidden_kernel(const float* __restrict__ embed,
                              const float* __restrict__ wdec,
                              const float* __restrict__ bdec,
                              const float* __restrict__ ctx,
                              unsigned short* __restrict__ h) {
    int t = threadIdx.x;                 // 0..127
    int r0 = blockIdx.x * 4;
    int d = blockIdx.y * 128 + t;
    __shared__ float e[4][DM];
    for (int i = 0; i < 4; i++) {
        for (int c = t; c < DM; c += 128)
            e[i][c] = embed[(size_t)EOS_ID * DM + c];
    }
    __syncthreads();
    float acc[4] = {0.f, 0.f, 0.f, 0.f};
#pragma unroll 2
    for (int k = 0; k < DM; k += 4) {
        float w[4];
#pragma unroll
        for (int q = 0; q < 4; q++) w[q] = wdec[(k + q) * DM + d];
#pragma unroll
        for (int i = 0; i < 4; i++) {
            float4 ev = *(const float4*)&e[i][k];
            acc[i] += ev.x * w[0]; acc[i] += ev.y * w[1];
            acc[i] += ev.z * w[2]; acc[i] += ev.w * w[3];
        }
    }
    float bb = bdec[d];
#pragma unroll
    for (int i = 0; i < 4; i++) {
        int r = r0 + i;
        int sent = (r & 31);
        h[r * DM + d] = f2bf(tanhf(acc[i] + bb + ctx[sent * DM + d]));
    }
}

// ----------------------------------- MFMA logits GEMM + fused softmax/top4
// R1 verbatim.
__global__ void __launch_bounds__(256, 2)
gemm_topk(const unsigned short* __restrict__ hb,
          const unsigned short* __restrict__ ebf,
          float* __restrict__ pm, float* __restrict__ ps,
          float* __restrict__ pv, int* __restrict__ pi,
          int step0, int ensure) {
    __shared__ char smem[16384];
    short* As = (short*)smem;
    short* Bs = (short*)(smem + 8192);
    int t = threadIdx.x;
    int v0 = blockIdx.x * 128;
    int w = t >> 6, lane = t & 63;
    int quad = lane >> 4, lr = lane & 15;
    int vh = w & 1, hh = w >> 1;
    int row2 = t >> 1, khalf = t & 1;

    f32x4 acc[4][4];
#pragma unroll
    for (int i = 0; i < 4; i++)
#pragma unroll
        for (int j = 0; j < 4; j++) acc[i][j] = (f32x4){0.f, 0.f, 0.f, 0.f};

    int arow = v0 + row2;
    bool aval = arow < VOCAB;
    const unsigned short* ga = ebf + (size_t)(aval ? arow : 0) * DM + khalf * 16;
    const unsigned short* gb = hb + row2 * DM + khalf * 16;

    uint4 a0_0 = *(const uint4*)(ga);
    uint4 a1_0 = *(const uint4*)(ga + 8);
    uint4 b0_0 = *(const uint4*)(gb);
    uint4 b1_0 = *(const uint4*)(gb + 8);
    uint4 a0_1 = *(const uint4*)(ga + 32);
    uint4 a1_1 = *(const uint4*)(ga + 40);
    uint4 b0_1 = *(const uint4*)(gb + 32);
    uint4 b1_1 = *(const uint4*)(gb + 40);

    auto kstep = [&](uint4& A0, uint4& A1, uint4& B0, uint4& B1, int kc) {
        if (!aval) {
            A0 = make_uint4(0u, 0u, 0u, 0u);
            A1 = make_uint4(0u, 0u, 0u, 0u);
        }
        __syncthreads();
        *(uint4*)(As + (khalf * 2) * 1024 + row2 * 8)     = A0;
        *(uint4*)(As + (khalf * 2 + 1) * 1024 + row2 * 8) = A1;
        *(uint4*)(Bs + (khalf * 2) * 1024 + row2 * 8)     = B0;
        *(uint4*)(Bs + (khalf * 2 + 1) * 1024 + row2 * 8) = B1;
        __syncthreads();
        if (kc + 64 < DM) {
            A0 = *(const uint4*)(ga + kc + 64);
            A1 = *(const uint4*)(ga + kc + 72);
            B0 = *(const uint4*)(gb + kc + 64);
            B1 = *(const uint4*)(gb + kc + 72);
        }
        bf16x8 af[4], bfr[4];
#pragma unroll
        for (int i = 0; i < 4; i++)
            af[i] = *(bf16x8*)(As + quad * 1024 + (64 * vh + 16 * i + lr) * 8);
#pragma unroll
        for (int j = 0; j < 4; j++)
            bfr[j] = *(bf16x8*)(Bs + quad * 1024 + (64 * hh + 16 * j + lr) * 8);
#pragma unroll
        for (int i = 0; i < 4; i++)
#pragma unroll
            for (int j = 0; j < 4; j++)
                acc[i][j] = __builtin_amdgcn_mfma_f32_16x16x32_bf16(
                    af[i], bfr[j], acc[i][j], 0, 0, 0);
    };

#pragma unroll
    for (int kc = 0; kc < DM; kc += 64) {
        kstep(a0_0, a1_0, b0_0, b1_0, kc);
        kstep(a0_1, a1_1, b0_1, b1_1, kc + 32);
    }
    __syncthreads();

    float* epim = (float*)smem;            // [128][2]
    float* epis = (float*)(smem + 1024);   // [128][2]
    float* epiv = (float*)(smem + 2048);   // [128][2][4]
    int*   epii = (int*)(smem + 6144);     // [128][2][4]

#pragma unroll
    for (int j = 0; j < 4; j++) {
        float m = -FLT_MAX, ssum = 0.f;
        float tv4[4] = {-FLT_MAX, -FLT_MAX, -FLT_MAX, -FLT_MAX};
        int ti4[4] = {0x7fffffff, 0x7fffffff, 0x7fffffff, 0x7fffffff};
#pragma unroll
        for (int i = 0; i < 4; i++)
#pragma unroll
            for (int reg = 0; reg < 4; reg++) {
                int v = v0 + 64 * vh + 16 * i + quad * 4 + reg;
                if (v < VOCAB) m = fmaxf(m, acc[i][j][reg]);
            }
#pragma unroll
        for (int i = 0; i < 4; i++)
#pragma unroll
            for (int reg = 0; reg < 4; reg++) {
                int v = v0 + 64 * vh + 16 * i + quad * 4 + reg;  // ascending
                if (v >= VOCAB) continue;
                float raw = acc[i][j][reg];
                ssum += __expf(raw - m);
                float mv = raw;
                if (v == PAD_ID) mv = NEG;
                if (step0 && v == EOS_ID) mv = NEG;
                if (ensure && v != EOS_ID) mv = NEG;
                if (mv > tv4[3]) {   // strict > keeps earliest (smallest v)
                    tv4[3] = mv; ti4[3] = v;
                    if (tv4[3] > tv4[2]) { float a = tv4[3]; tv4[3] = tv4[2]; tv4[2] = a; int b = ti4[3]; ti4[3] = ti4[2]; ti4[2] = b; }
                    if (tv4[2] > tv4[1]) { float a = tv4[2]; tv4[2] = tv4[1]; tv4[1] = a; int b = ti4[2]; ti4[2] = ti4[1]; ti4[1] = b; }
                    if (tv4[1] > tv4[0]) { float a = tv4[1]; tv4[1] = tv4[0]; tv4[0] = a; int b = ti4[1]; ti4[1] = ti4[0]; ti4[0] = b; }
                }
            }
#pragma unroll
        for (int mask = 16; mask <= 32; mask <<= 1) {
            float om = __shfl_xor(m, mask);
            float os = __shfl_xor(ssum, mask);
            float ov[4]; int oi[4];
#pragma unroll
            for (int c = 0; c < 4; c++) {
                ov[c] = __shfl_xor(tv4[c], mask);
                oi[c] = __shfl_xor(ti4[c], mask);
            }
            osm_merge(m, ssum, om, os);
            merge4(tv4, ti4, ov, oi);
        }
        if (quad == 0) {
            int hrow = 64 * hh + 16 * j + lr;
            int slot = hrow * 2 + vh;
            epim[slot] = m; epis[slot] = ssum;
#pragma unroll
            for (int c = 0; c < 4; c++) { epiv[slot * 4 + c] = tv4[c]; epii[slot * 4 + c] = ti4[c]; }
        }
    }
    __syncthreads();
    if (t < 128) {
        int s0 = t * 2, s1 = t * 2 + 1;
        float m = epim[s0], ssum = epis[s0];
        float tv4[4]; int ti4[4];
#pragma unroll
        for (int c = 0; c < 4; c++) { tv4[c] = epiv[s0 * 4 + c]; ti4[c] = epii[s0 * 4 + c]; }
        float ov[4]; int oi[4];
#pragma unroll
        for (int c = 0; c < 4; c++) { ov[c] = epiv[s1 * 4 + c]; oi[c] = epii[s1 * 4 + c]; }
        osm_merge(m, ssum, epim[s1], epis[s1]);
        merge4(tv4, ti4, ov, oi);
        int pidx = t * VB + blockIdx.x;
        pm[pidx] = m;
        ps[pidx] = ssum;
#pragma unroll
        for (int c = 0; c < 4; c++) { pv[pidx * 4 + c] = tv4[c]; pi[pidx * 4 + c] = ti4[c]; }
    }
}

// ------------------------------------------- fused beam update + next hidden
// R10: latency fixes, math bit-identical.
//  * wdec staged via async global_load_lds: 16 chunks x 32 k-rows, double-
//    buffered (32KB LDS). Chunk 0 issues BEFORE the beam phase (wdec doesn't
//    depend on beam result) and each __syncthreads drains vmcnt, so staging
//    latency hides under beam/FMA work. FMA reads come from LDS.
//  * partial-scan loop fully unrolled (7 fixed trips) so all ~70 loads can
//    hoist to one latency exposure; launch_bounds(256,1) frees VGPRs.
//  * all 256 threads compute (2 rows x 1 col each). Per-(row,col) FMA chain
//    is the same statements in the same k order -> bit-exact (absmax must
//    stay 46256).
__global__ void __launch_bounds__(256, 1)
beamhid(int s,
        const float* __restrict__ pm, const float* __restrict__ ps,
        const float* __restrict__ pv, const int* __restrict__ pi,
        const int* __restrict__ tok_cur, int* __restrict__ tok_nxt,
        const float* __restrict__ sc_cur, float* __restrict__ sc_nxt,
        const float* __restrict__ psc_cur, float* __restrict__ psc_nxt,
        const float* __restrict__ bf_cur, float* __restrict__ bf_nxt,
        const float* __restrict__ embed,
        const float* __restrict__ wdec,
        const float* __restrict__ bdec,
        const float* __restrict__ ctxv,
        unsigned short* __restrict__ h) {
    int blk = blockIdx.x, t = threadIdx.x;
    int rg = blk >> 2, q = blk & 3;
    __shared__ float r_cs[16], r_sent[16], r_ssel[4];
    __shared__ int r_ct[16], r_parent[4], r_tsel[4];
    __shared__ float e[4][DM];              // 8 KB
    __shared__ float wlds[2][32][128];      // 32 KB double-buffered wdec chunk

    // stage one 32x128 wdec chunk (16KB) into wlds[buf]: 4 async insts,
    // LDS dest lane-linear (base wave-uniform, +lane*16B), global per-lane.
    auto stage = [&](int buf, int chunk) {
#pragma unroll
        for (int inst = 0; inst < 4; inst++) {
            int f = inst * 1024 + t * 4;          // float idx in 32x128 tile
            int kk = f >> 7, col = f & 127;
            const float* g = wdec + (size_t)(chunk * 32 + kk) * DM + q * 128 + col;
            char* l = (char*)&wlds[0][0][0] + buf * 16384 + inst * 4096 + (t >> 6) * 1024;
            gll16(g, l);
        }
    };
    if (s < TGT) stage(0, 0);   // in flight during the whole beam phase

    if (s == 0) {
        // ---- reduce_init (wave 0), unrolled scan ----
        if (t < 64) {
            int lane = t;
            float m = -FLT_MAX, ssum = 0.f;
            float tv4[4] = {-FLT_MAX, -FLT_MAX, -FLT_MAX, -FLT_MAX};
            int ti4[4] = {0x7fffffff, 0x7fffffff, 0x7fffffff, 0x7fffffff};
#pragma unroll
            for (int jj = 0; jj < 7; jj++) {
                int j = lane + jj * 64;
                if (j < VB) {
                    int pidx = rg * VB + j;
                    float ov[4]; int oi[4];
#pragma unroll
                    for (int c = 0; c < 4; c++) { ov[c] = pv[pidx * 4 + c]; oi[c] = pi[pidx * 4 + c]; }
                    osm_merge(m, ssum, pm[pidx], ps[pidx]);
                    merge4(tv4, ti4, ov, oi);
                }
            }
#pragma unroll
            for (int mask = 1; mask <= 32; mask <<= 1) {
                float om = __shfl_xor(m, mask);
                float os = __shfl_xor(ssum, mask);
                float ov[4]; int oi[4];
#pragma unroll
                for (int c = 0; c < 4; c++) {
                    ov[c] = __shfl_xor(tv4[c], mask);
                    oi[c] = __shfl_xor(ti4[c], mask);
                }
                osm_merge(m, ssum, om, os);
                merge4(tv4, ti4, ov, oi);
            }
            if (lane == 0) {
                float lse_b = m + logf(ssum);
                for (int c = 0; c < 4; c++) {
                    float val = tv4[c];
                    float sc = (val < -9.0e29f) ? NEG : (val - lse_b);
                    if (sc < -9.0e29f) sc = NEG;
                    r_tsel[c] = ti4[c]; r_ssel[c] = sc;
                    psc_nxt[rg * 4 + c] = sc;
                }
                bf_nxt[rg] = NEG;
            }
        }
        __syncthreads();
        for (int idx = t; idx < 4 * TOKC; idx += 256) {
            int i = idx / TOKC, c = idx % TOKC;
            int dst = rg * 4 + i;
            tok_nxt[dst * TOKC + c] = (c == 0) ? EOS_ID : ((c == 1) ? r_tsel[i] : PAD_ID);
            if (c < SCC) sc_nxt[dst * SCC + c] = (c == 0) ? r_ssel[i] : NEG;
        }
    } else {
        // ---- reduce_beam, unrolled scan ----
        int g = t >> 6, lane = t & 63;
        int r = rg * 4 + g;
        float m = -FLT_MAX, ssum = 0.f;
        float tv4[4] = {-FLT_MAX, -FLT_MAX, -FLT_MAX, -FLT_MAX};
        int ti4[4] = {0x7fffffff, 0x7fffffff, 0x7fffffff, 0x7fffffff};
#pragma unroll
        for (int jj = 0; jj < 7; jj++) {
            int j = lane + jj * 64;
            if (j < VB) {
                int pidx = r * VB + j;
                float ov[4]; int oi[4];
#pragma unroll
                for (int c = 0; c < 4; c++) { ov[c] = pv[pidx * 4 + c]; oi[c] = pi[pidx * 4 + c]; }
                osm_merge(m, ssum, pm[pidx], ps[pidx]);
                merge4(tv4, ti4, ov, oi);
            }
        }
#pragma unroll
        for (int mask = 1; mask <= 32; mask <<= 1) {
            float om = __shfl_xor(m, mask);
            float os = __shfl_xor(ssum, mask);
            float ov[4]; int oi[4];
#pragma unroll
            for (int c = 0; c < 4; c++) {
                ov[c] = __shfl_xor(tv4[c], mask);
                oi[c] = __shfl_xor(ti4[c], mask);
            }
            osm_merge(m, ssum, om, os);
            merge4(tv4, ti4, ov, oi);
        }
        if (lane == 0) {
            float lse_r = m + logf(ssum);
            float prev = psc_cur[r];
            for (int c = 0; c < 4; c++) {
                float val = tv4[c];
                float lp = (val < -9.0e29f) ? NEG : (val - lse_r);
                float csv = lp + prev;
                if (csv < -9.0e29f) csv = NEG;
                r_cs[g * 4 + c] = csv;
                r_sent[g * 4 + c] = csv / (float)(s + 1);
                r_ct[g * 4 + c] = ti4[c];
            }
        }
        __syncthreads();
        if (t == 0) {
            int top[8], c2[8];
            float s2[8], cs2[8];
            unsigned used = 0;
            for (int o = 0; o < 8; o++) {
                float best = -FLT_MAX; int bi = 0;
                for (int i = 0; i < 16; i++)
                    if (!((used >> i) & 1u) && r_sent[i] > best) { best = r_sent[i]; bi = i; }
                used |= 1u << bi;
                top[o] = bi; s2[o] = best; c2[o] = r_ct[bi]; cs2[o] = r_cs[bi];
            }
            float bf = bf_cur[rg];
            for (int c = 0; c < 4; c++)
                if (c2[c] == EOS_ID) bf = fmaxf(bf, s2[c]);
            bf_nxt[rg] = bf;
            float sm[8];
            for (int c = 0; c < 8; c++) sm[c] = (c2[c] == EOS_ID) ? NEG : s2[c];
            unsigned used2 = 0;
            for (int o = 0; o < 4; o++) {
                float best = -FLT_MAX; int bi = 0;
                for (int i = 0; i < 8; i++)
                    if (!((used2 >> i) & 1u) && sm[i] > best) { best = sm[i]; bi = i; }
                used2 |= 1u << bi;
                r_parent[o] = top[bi] >> 2;
                r_tsel[o] = c2[bi];
                float sv = cs2[bi];
                if (sv < -9.0e29f) sv = NEG;
                r_ssel[o] = sv;
            }
            for (int o = 0; o < 4; o++)
                psc_nxt[rg * 4 + o] = r_ssel[o];
        }
        __syncthreads();
        for (int idx = t; idx < 4 * TOKC; idx += 256) {
            int i = idx / TOKC, c = idx % TOKC;
            int srcr = rg * 4 + r_parent[i], dst = rg * 4 + i;
            tok_nxt[dst * TOKC + c] = (c == s + 1) ? r_tsel[i] : tok_cur[srcr * TOKC + c];
            if (c < SCC)
                sc_nxt[dst * SCC + c] = (c == s) ? r_ssel[i] : sc_cur[srcr * SCC + c];
        }
    }

    // ---- next-step h rows for sentence rg, col slice q ----
    if (s < TGT) {
        // e staging (needs r_tsel, already visible: both branches synced
        // after r_tsel was written)
        for (int idx = t; idx < 4 * DM; idx += 256) {
            int i = idx >> 9, c = idx & 511;
            e[i][c] = embed[(size_t)r_tsel[i] * DM + c];
        }
        int col = t & 127, rr = t >> 7;       // 2 rows x 1 col per thread
        int d = q * 128 + col;
        float a0 = 0.f, a1 = 0.f;
        for (int ch = 0; ch < 16; ch++) {
            __syncthreads();                  // drains stage(ch); e ready at ch=0
            if (ch + 1 < 16) stage((ch + 1) & 1, ch + 1);
            const float* wb = &wlds[ch & 1][0][0];
            int K0 = ch * 32;
#pragma unroll
            for (int kk = 0; kk < 32; kk += 4) {
                float4 e0 = *(const float4*)&e[2 * rr][K0 + kk];
                float4 e1 = *(const float4*)&e[2 * rr + 1][K0 + kk];
                float w0 = wb[(kk + 0) * 128 + col];
                float w1 = wb[(kk + 1) * 128 + col];
                float w2 = wb[(kk + 2) * 128 + col];
                float w3 = wb[(kk + 3) * 128 + col];
                a0 += e0.x * w0; a0 += e0.y * w1; a0 += e0.z * w2; a0 += e0.w * w3;
                a1 += e1.x * w0; a1 += e1.y * w1; a1 += e1.z * w2; a1 += e1.w * w3;
            }
        }
        float bb = bdec[d];
        float cx = ctxv[rg * DM + d];
        h[(rg * 4 + 2 * rr) * DM + d]     = f2bf(tanhf(a0 + bb + cx));
        h[(rg * 4 + 2 * rr + 1) * DM + d] = f2bf(tanhf(a1 + bb + cx));
    }
}

// ---------------------------------------------------------------- finalize
__global__ void finalize_kernel(const int* __restrict__ tok,
                                const float* __restrict__ sc,
                                const float* __restrict__ bf,
                                float* __restrict__ out) {
    int i = blockIdx.x * 256 + threadIdx.x;
    const int NTOK = 128 * TOKC;        // 6400
    const int NSC = 128 * SCC;          // 6272
    const int TOT = NTOK + NSC + 32;    // 12704
    if (i >= TOT) return;
    float v;
    if (i < NTOK) {
        int tv = tok[i];
        if (tv < 0) tv = 0;
        if (tv > VOCAB - 1) tv = VOCAB - 1;
        v = (float)tv;
    } else {
        v = (i < NTOK + NSC) ? sc[i - NTOK] : bf[i - NTOK - NSC];
        if (!(v <= 0.0f)) v = 0.0f;
        if (v < -9.0e29f) v = NEG;
    }
    out[i] = v;
}

// ---------------------------------------------------------------- launch
extern "C" void kernel_launch(void* const* d_in, const int* in_sizes, int n_in,
                              void* d_out, int out_size, void* d_ws, size_t ws_size,
                              hipStream_t stream) {
    const int* src = (const int*)d_in[0];
    const float* embed = (const float*)d_in[1];
    const float* wenc = (const float*)d_in[2];
    const float* wdec = (const float*)d_in[3];
    const float* bdec = (const float*)d_in[4];

    char* w = (char*)d_ws;
    size_t off = 0;
    auto alloc = [&](size_t bytes) -> char* {
        char* p = w + off;
        off += (bytes + 255) & ~(size_t)255;
        return p;
    };
    float* psb0   = (float*)alloc(128 * 4);
    float* psb1   = (float*)alloc(128 * 4);
    float* bfb0   = (float*)alloc(BSZ * 4);
    float* bfb1   = (float*)alloc(BSZ * 4);
    int*   tokb0  = (int*)alloc(128 * TOKC * 4);
    int*   tokb1  = (int*)alloc(128 * TOKC * 4);
    float* scb0   = (float*)alloc(128 * SCC * 4);
    float* scb1   = (float*)alloc(128 * SCC * 4);
    unsigned short* h = (unsigned short*)alloc((size_t)128 * DM * 2);
    float* ctx    = (float*)alloc((size_t)BSZ * DM * 4);
    float* encpart= (float*)alloc((size_t)BSZ * 8 * DM * 4);
    const size_t NP = (size_t)128 * VB;
    float* pm = (float*)alloc(NP * 4);
    float* ps = (float*)alloc(NP * 4);
    float* pv = (float*)alloc(NP * 4 * 4);
    int*   pi = (int*)alloc(NP * 4 * 4);
    unsigned short* ebf = (unsigned short*)alloc((size_t)VOCAB * DM * 2);
    int* tokb[2] = {tokb0, tokb1};
    float* scb[2] = {scb0, scb1};
    float* psb[2] = {psb0, psb1};
    float* bfb[2] = {bfb0, bfb1};

    // one-time embed -> bf16 (RNE identical to old in-gemm pkbf)
    embed2bf_kernel<<<(VOCAB * DM / 8 + 255) / 256, 256, 0, stream>>>(embed, ebf);

    // encoder context
    ctx_partial_kernel<<<dim3(BSZ, 8), 512, 0, stream>>>(src, embed, wenc, encpart);
    ctx_reduce_kernel<<<BSZ, 512, 0, stream>>>(encpart, ctx);

    // step-0 hidden (all rows EOS)
    hidden_kernel<<<dim3(32, 4), 128, 0, stream>>>(embed, wdec, bdec, ctx, h);

    // steps 0..48: gemm+topk, then fused beam-update + next hidden
    for (int s = 0; s <= TGT; s++) {
        gemm_topk<<<VB, 256, 0, stream>>>(h, ebf, pm, ps, pv, pi,
                                          (s == 0) ? 1 : 0, (s == TGT) ? 1 : 0);
        int cur = (s == 0) ? 1 : ((s - 1) & 1);   // s=0: cur unread
        int nxt = s & 1;                           // s=0 -> 0
        beamhid<<<128, 256, 0, stream>>>(s, pm, ps, pv, pi,
                                         tokb[cur], tokb[nxt], scb[cur], scb[nxt],
                                         psb[cur], psb[nxt], bfb[cur], bfb[nxt],
                                         embed, wdec, bdec, ctx, h);
    }

    // final parity: step 48 wrote buffer 0
    finalize_kernel<<<50, 256, 0, stream>>>(tokb[0], scb[0], bfb[0],
                                            (float*)d_out);
}